// Round 9
// baseline (935.931 us; speedup 1.0000x reference)
//
#include <hip/hip_runtime.h>
#include <math.h>

#define DD    128
#define NQQ   7
#define NB    1024
#define TRI   8256
#define CSTR  136        // bf16 elems per chunk row (272 B, 16B-aligned granules)

typedef short  bf16x8 __attribute__((ext_vector_type(8)));
typedef short  s16x4  __attribute__((ext_vector_type(4)));
typedef float  f32x16 __attribute__((ext_vector_type(16)));

// truncation hi/lo split: hi = top16(v), lo = top16(v - hi)
__device__ __forceinline__ void split2(float v, unsigned short& h, unsigned short& l) {
  unsigned u = __builtin_bit_cast(unsigned, v);
  float hf = __builtin_bit_cast(float, u & 0xFFFF0000u);
  float lf = v - hf;
  h = (unsigned short)(u >> 16);
  l = (unsigned short)(__builtin_bit_cast(unsigned, lf) >> 16);
}
__device__ __forceinline__ float bf2f(unsigned short s) {
  return __builtin_bit_cast(float, ((unsigned)s) << 16);
}
__device__ __forceinline__ f32x16 MF(bf16x8 a, bf16x8 b, f32x16 c) {
  return __builtin_amdgcn_mfma_f32_32x32x16_bf16(a, b, c, 0, 0, 0);
}
__device__ __forceinline__ bf16x8 NEG(bf16x8 a) {
  int4 u = __builtin_bit_cast(int4, a);
  u.x ^= 0x80008000; u.y ^= 0x80008000; u.z ^= 0x80008000; u.w ^= 0x80008000;
  return __builtin_bit_cast(bf16x8, u);
}
__device__ __forceinline__ bf16x8 LDF(const unsigned short* C, int row, int s, int hb) {
  return *reinterpret_cast<const bf16x8*>(C + row * CSTR + s * 16 + hb * 8);
}

// 1024 threads = 16 waves; each wave owns ONE 32x32 output tile (tr,tc).
// Live chain accumulators per wave: Cc,Qc,p = 48 VGPRs of f32x16 (vs 96 at
// 8 waves) -> target: zero scratch (R5-R7: 315MB/dispatch scratch writes).
__global__ __launch_bounds__(1024) void loss_k(
    const float* __restrict__ flat,
    const float* __restrict__ timev,
    const float* __restrict__ state,
    const int*   __restrict__ tgt,
    const int*   __restrict__ basis,
    float* __restrict__ ws)
{
  __shared__ __align__(16) char lds[4 * 128 * CSTR * 2 + 8192];
  unsigned short* C0 = (unsigned short*)lds;
  unsigned short* C1 = C0 + 128 * CSTR;
  unsigned short* C2 = C1 + 128 * CSTR;
  unsigned short* C3 = C2 + 128 * CSTR;
  float* AUX = (float*)(lds + 4 * 128 * CSTR * 2);   // 2048 floats

  const int b    = blockIdx.x;
  const int tid  = threadIdx.x;
  const int wid  = tid >> 6;          // 0..15
  const int lane = tid & 63;
  const int l31  = lane & 31;
  const int hb   = lane >> 5;

  const int tr   = wid >> 2;          // tile-row 0..3
  const int tc   = wid & 3;           // tile-col 0..3
  const int arow = 32 * tr + l31;
  const int bcol = 32 * tc + l31;

  const float tval  = timev[b];
  const float alpha = 0.25f * tval * 0.25f;     // DS * t / 2^2 (2 squarings)
  const float* fb = flat + (size_t)b * TRI;

#define STORE_TILE(PREG, SCALE, DH, DL) do {                               \
    _Pragma("unroll")                                                      \
    for (int q_ = 0; q_ < 4; ++q_) {                                       \
      s16x4 hh_, ll_;                                                      \
      _Pragma("unroll")                                                    \
      for (int rr_ = 0; rr_ < 4; ++rr_) {                                  \
        unsigned short h_, l_;                                             \
        split2((SCALE) * (PREG)[4 * q_ + rr_], h_, l_);                    \
        hh_[rr_] = (short)h_; ll_[rr_] = (short)l_;                        \
      }                                                                    \
      int off_ = bcol * CSTR + 32 * tr + 8 * q_ + 4 * hb;                  \
      *(s16x4*)((DH) + off_) = hh_; *(s16x4*)((DL) + off_) = ll_;          \
    }                                                                      \
  } while (0)

  // p = A @ B (3-product bf16 hi/lo split), A rows from (AH,AL), B cols from (BH,BL)
#define PROD(AH, AL, BH, BL) do {                                          \
    _Pragma("unroll")                                                      \
    for (int e_ = 0; e_ < 16; ++e_) p[e_] = 0.0f;                          \
    _Pragma("unroll")                                                      \
    for (int s_ = 0; s_ < 8; ++s_) {                                       \
      bf16x8 ah_ = LDF(AH, arow, s_, hb), al_ = LDF(AL, arow, s_, hb);     \
      bf16x8 bh_ = LDF(BH, bcol, s_, hb), bl_ = LDF(BL, bcol, s_, hb);     \
      p = MF(ah_, bh_, p); p = MF(ah_, bl_, p); p = MF(al_, bh_, p);       \
    }                                                                      \
  } while (0)

  // ---- Phase 0: stage X = alpha*M into C0/C1 (hi/lo) ----
  for (int e = tid; e < DD * DD; e += 1024) {
    int i = e >> 7, j = e & 127;
    int r = i >= j ? i : j, c = i >= j ? j : i;
    float v = alpha * fb[(r * (r + 1)) / 2 + c];
    unsigned short h, l; split2(v, h, l);
    C0[i * CSTR + j] = h;  C1[i * CSTR + j] = l;
  }
  __syncthreads();

  f32x16 p, Cc, Qc;

  // ---- Y = X @ X ;  C = I - Y/2, Q = I - Y/6 ;  Y -> C2/C3 ----
  PROD(C0, C1, C0, C1);
  __syncthreads();
#pragma unroll
  for (int q = 0; q < 4; ++q) {
#pragma unroll
    for (int rr = 0; rr < 4; ++rr) {
      int e = 4 * q + rr;
      float i0 = ((32 * tr + 8 * q + 4 * hb + rr) == bcol) ? 1.0f : 0.0f;
      Cc[e] = i0 - 0.5f * p[e];
      Qc[e] = i0 - 0.16666667f * p[e];
    }
  }
  STORE_TILE(p, 1.0f, C2, C3);
  __syncthreads();

  // ---- Z2 = Y @ Y -> C0/C1 (X dead, rebuilt later) ----
  PROD(C2, C3, C2, C3);
  __syncthreads();
#pragma unroll
  for (int e = 0; e < 16; ++e) {
    Cc[e] += 4.1666668e-2f * p[e];
    Qc[e] += 8.3333333e-3f * p[e];
  }
  STORE_TILE(p, 1.0f, C0, C1);
  __syncthreads();

  // ---- j-steps: Z_j = Y @ Z_{j-1}; literal coefficients, no arrays ----
#define JSTEP(CJLIT, QJLIT, DO_STORE) do {                                 \
    PROD(C2, C3, C0, C1);                                                  \
    __syncthreads();                                                       \
    _Pragma("unroll")                                                      \
    for (int e_ = 0; e_ < 16; ++e_) Cc[e_] += (CJLIT) * p[e_];             \
    if (DO_STORE) {                                                        \
      _Pragma("unroll")                                                    \
      for (int e_ = 0; e_ < 16; ++e_) Qc[e_] += (QJLIT) * p[e_];           \
      STORE_TILE(p, 1.0f, C0, C1);                                         \
    }                                                                      \
    __syncthreads();                                                       \
  } while (0)

  JSTEP(-1.3888889e-3f,  -1.9841270e-4f,  1);   // j=3
  JSTEP( 2.4801587e-5f,   2.7557319e-6f,  1);   // j=4
  JSTEP(-2.7557319e-7f,  -2.5052108e-8f,  1);   // j=5
  JSTEP( 2.0876757e-9f,   1.6059044e-10f, 1);   // j=6
  JSTEP(-1.1470746e-11f, -7.6471637e-13f, 1);   // j=7
  JSTEP( 4.7794773e-14f,  0.0f,           0);   // j=8 (C only)
#undef JSTEP

  // ---- Q -> C2/C3 (over Y); rebuild X -> C0/C1 (over Z7) ----
  STORE_TILE(Qc, 1.0f, C2, C3);
  for (int e = tid; e < DD * DD; e += 1024) {
    int i = e >> 7, j = e & 127;
    int r = i >= j ? i : j, c = i >= j ? j : i;
    float v = alpha * fb[(r * (r + 1)) / 2 + c];
    unsigned short h, l; split2(v, h, l);
    C0[i * CSTR + j] = h;  C1[i * CSTR + j] = l;
  }
  __syncthreads();

  // ---- S = X @ Q (sin);  then U0 = cos - i sin into chunks ----
  PROD(C0, C1, C2, C3);
  __syncthreads();
  STORE_TILE(Cc, 1.0f, C0, C1);       // Re
  STORE_TILE(p, -1.0f, C2, C3);       // Im = -sin
  __syncthreads();

  // ---- 2 squarings: Re' = R@R - I@I ; Im' = 2*(R@I)  (commuting) ----
  for (int sq = 0; sq < 2; ++sq) {
    f32x16 cr, ci;
#pragma unroll
    for (int e = 0; e < 16; ++e) { cr[e] = 0.0f; ci[e] = 0.0f; }
#pragma unroll
    for (int s = 0; s < 8; ++s) {
      bf16x8 aRh = LDF(C0, arow, s, hb), aRl = LDF(C1, arow, s, hb);
      bf16x8 aIh = LDF(C2, arow, s, hb), aIl = LDF(C3, arow, s, hb);
      bf16x8 bRh = LDF(C0, bcol, s, hb), bRl = LDF(C1, bcol, s, hb);
      bf16x8 bIh = LDF(C2, bcol, s, hb), bIl = LDF(C3, bcol, s, hb);
      cr = MF(aRh, bRh, cr); cr = MF(aRh, bRl, cr); cr = MF(aRl, bRh, cr);
      bf16x8 nIh = NEG(aIh), nIl = NEG(aIl);
      cr = MF(nIh, bIh, cr); cr = MF(nIh, bIl, cr); cr = MF(nIl, bIh, cr);
      ci = MF(aRh, bIh, ci); ci = MF(aRh, bIl, ci); ci = MF(aRl, bIh, ci);
    }
    __syncthreads();
    STORE_TILE(cr, 1.0f, C0, C1);
    STORE_TILE(ci, 2.0f, C2, C3);
    __syncthreads();
  }

  // ---- Butterfly G = F @ U directly on bf16 hi/lo chunks ----
  const int* bq = basis + b * NQQ;
  const float sv = 0.70710678118654752f;
  for (int q = 0; q < NQQ; ++q) {
    int g = bq[q];
    if (g == 2) continue;            // uniform branch
    const int bit = 6 - q;
    float g00r, g01r, g01i, g10r, g11r, g11i;
    if (g == 0) { g00r = sv; g01r = sv; g01i = 0;   g10r = sv; g11r = -sv; g11i = 0;  }
    else        { g00r = sv; g01r = 0;  g01i = -sv; g10r = sv; g11r = 0;   g11i = sv; }
#pragma unroll 1
    for (int jj = tid; jj < 64 * 32; jj += 1024) {
      int cg = jj & 31;              // column group of 4
      int pr = jj >> 5;              // pair 0..63
      int low = pr & ((1 << bit) - 1);
      int i0 = ((pr >> bit) << (bit + 1)) | low;
      int i1 = i0 | (1 << bit);
      int base0 = i0 * CSTR + 4 * cg;
      int base1 = i1 * CSTR + 4 * cg;
      s16x4 A0h = *(s16x4*)(C0 + base0), A0l = *(s16x4*)(C1 + base0);
      s16x4 B0h = *(s16x4*)(C2 + base0), B0l = *(s16x4*)(C3 + base0);
      s16x4 A1h = *(s16x4*)(C0 + base1), A1l = *(s16x4*)(C1 + base1);
      s16x4 B1h = *(s16x4*)(C2 + base1), B1l = *(s16x4*)(C3 + base1);
      s16x4 oA0h, oA0l, oB0h, oB0l, oA1h, oA1l, oB1h, oB1l;
#pragma unroll
      for (int d = 0; d < 4; ++d) {
        float a0 = bf2f((unsigned short)A0h[d]) + bf2f((unsigned short)A0l[d]);
        float b0 = bf2f((unsigned short)B0h[d]) + bf2f((unsigned short)B0l[d]);
        float a1 = bf2f((unsigned short)A1h[d]) + bf2f((unsigned short)A1l[d]);
        float b1 = bf2f((unsigned short)B1h[d]) + bf2f((unsigned short)B1l[d]);
        float n0r = g00r * a0 + g01r * a1 - g01i * b1;
        float n0i = g00r * b0 + g01r * b1 + g01i * a1;
        float n1r = g10r * a0 + g11r * a1 - g11i * b1;
        float n1i = g10r * b0 + g11r * b1 + g11i * a1;
        unsigned short h, l;
        split2(n0r, h, l); oA0h[d] = (short)h; oA0l[d] = (short)l;
        split2(n0i, h, l); oB0h[d] = (short)h; oB0l[d] = (short)l;
        split2(n1r, h, l); oA1h[d] = (short)h; oA1l[d] = (short)l;
        split2(n1i, h, l); oB1h[d] = (short)h; oB1l[d] = (short)l;
      }
      *(s16x4*)(C0 + base0) = oA0h; *(s16x4*)(C1 + base0) = oA0l;
      *(s16x4*)(C2 + base0) = oB0h; *(s16x4*)(C3 + base0) = oB0l;
      *(s16x4*)(C0 + base1) = oA1h; *(s16x4*)(C1 + base1) = oA1l;
      *(s16x4*)(C2 + base1) = oB1h; *(s16x4*)(C3 + base1) = oB1l;
    }
    __syncthreads();
  }

  // ---- Phase 4: W = rho @ conj(G)^T (MFMA); d_i = sum_k G_ik W_ki ----
  // 16 waves = part(2) x slab(4) x colpair(2); w0,w1 only (32 VGPR live).
  const int part = wid >> 3;           // 0: Wr, 1: Wi
  const int slab = (wid >> 1) & 3;     // W row-block
  const int n40  = (wid & 1) * 2;      // col tiles n40, n40+1
  const int n41  = n40 + 1;
  const float* srow = state + (size_t)b * (DD * DD * 2) + (size_t)(32 * slab + l31) * 256;

  f32x16 w0, w1;
#pragma unroll
  for (int e = 0; e < 16; ++e) { w0[e] = 0.0f; w1[e] = 0.0f; }

  for (int s = 0; s < 8; ++s) {
    const float* pp = srow + (s * 16 + hb * 8) * 2;
    float4 q0 = *(const float4*)(pp);
    float4 q1 = *(const float4*)(pp + 4);
    float4 q2 = *(const float4*)(pp + 8);
    float4 q3 = *(const float4*)(pp + 12);
    bf16x8 rh, rl, ihh, ill;
    {
      unsigned short h, l;
      split2(q0.x, h, l); rh[0] = (short)h; rl[0] = (short)l;
      split2(q0.z, h, l); rh[1] = (short)h; rl[1] = (short)l;
      split2(q1.x, h, l); rh[2] = (short)h; rl[2] = (short)l;
      split2(q1.z, h, l); rh[3] = (short)h; rl[3] = (short)l;
      split2(q2.x, h, l); rh[4] = (short)h; rl[4] = (short)l;
      split2(q2.z, h, l); rh[5] = (short)h; rl[5] = (short)l;
      split2(q3.x, h, l); rh[6] = (short)h; rl[6] = (short)l;
      split2(q3.z, h, l); rh[7] = (short)h; rl[7] = (short)l;
      split2(q0.y, h, l); ihh[0] = (short)h; ill[0] = (short)l;
      split2(q0.w, h, l); ihh[1] = (short)h; ill[1] = (short)l;
      split2(q1.y, h, l); ihh[2] = (short)h; ill[2] = (short)l;
      split2(q1.w, h, l); ihh[3] = (short)h; ill[3] = (short)l;
      split2(q2.y, h, l); ihh[4] = (short)h; ill[4] = (short)l;
      split2(q2.w, h, l); ihh[5] = (short)h; ill[5] = (short)l;
      split2(q3.y, h, l); ihh[6] = (short)h; ill[6] = (short)l;
      split2(q3.w, h, l); ihh[7] = (short)h; ill[7] = (short)l;
    }
    bf16x8 rhn = NEG(rh), rln = NEG(rl);
#define P4N4(WREG, N4) do {                                                \
    int gcol_ = 32 * (N4) + l31;                                           \
    bf16x8 gRh = LDF(C0, gcol_, s, hb), gRl = LDF(C1, gcol_, s, hb);       \
    bf16x8 gIh = LDF(C2, gcol_, s, hb), gIl = LDF(C3, gcol_, s, hb);       \
    if (part == 0) {                                                       \
      WREG = MF(rh, gRh, WREG);  WREG = MF(rh, gRl, WREG);  WREG = MF(rl, gRh, WREG); \
      WREG = MF(ihh, gIh, WREG); WREG = MF(ihh, gIl, WREG); WREG = MF(ill, gIh, WREG); \
    } else {                                                               \
      WREG = MF(ihh, gRh, WREG); WREG = MF(ihh, gRl, WREG); WREG = MF(ill, gRh, WREG); \
      WREG = MF(rhn, gIh, WREG); WREG = MF(rhn, gIl, WREG); WREG = MF(rln, gIh, WREG); \
    }                                                                      \
  } while (0)
    P4N4(w0, n40); P4N4(w1, n41);
#undef P4N4
  }

#define P4DOT(WREG, N4) do {                                               \
    int gcol_ = 32 * (N4) + l31;                                           \
    float a1 = 0.0f, a2 = 0.0f;                                            \
    _Pragma("unroll")                                                      \
    for (int q_ = 0; q_ < 4; ++q_) {                                       \
      int koff = 32 * slab + 8 * q_ + 4 * hb;                              \
      s16x4 grh = *(const s16x4*)(C0 + gcol_ * CSTR + koff);               \
      s16x4 grl = *(const s16x4*)(C1 + gcol_ * CSTR + koff);               \
      s16x4 gih = *(const s16x4*)(C2 + gcol_ * CSTR + koff);               \
      s16x4 gil = *(const s16x4*)(C3 + gcol_ * CSTR + koff);               \
      _Pragma("unroll")                                                    \
      for (int rr_ = 0; rr_ < 4; ++rr_) {                                  \
        float wv = WREG[4 * q_ + rr_];                                     \
        float gr = bf2f((unsigned short)grh[rr_]) + bf2f((unsigned short)grl[rr_]); \
        float gi = bf2f((unsigned short)gih[rr_]) + bf2f((unsigned short)gil[rr_]); \
        a1 = fmaf(gr, wv, a1); a2 = fmaf(gi, wv, a2);                      \
      }                                                                    \
    }                                                                      \
    a1 += __shfl_xor(a1, 32); a2 += __shfl_xor(a2, 32);                    \
    if (lane < 32) {                                                       \
      AUX[((part * 2 + 0) * 4 + slab) * 128 + 32 * (N4) + l31] = a1;       \
      AUX[((part * 2 + 1) * 4 + slab) * 128 + 32 * (N4) + l31] = a2;       \
    }                                                                      \
  } while (0)
  P4DOT(w0, n40); P4DOT(w1, n41);
#undef P4DOT
  __syncthreads();

  if (tid < 128) {
    float s0 = 0, s1 = 0, s2 = 0, s3 = 0;
#pragma unroll
    for (int sl = 0; sl < 4; ++sl) {
      s0 += AUX[(0 * 4 + sl) * 128 + tid];   // Gr.Wr
      s1 += AUX[(1 * 4 + sl) * 128 + tid];   // Gi.Wr
      s2 += AUX[(2 * 4 + sl) * 128 + tid];   // Gr.Wi
      s3 += AUX[(3 * 4 + sl) * 128 + tid];   // Gi.Wi
    }
    float dr = s0 - s3, di = s2 + s1;
    AUX[tid] = dr * dr + di * di;
  }
  __syncthreads();
  if (tid < 64) {
    float ps = AUX[tid] + AUX[tid + 64];
#pragma unroll
    for (int o = 32; o >= 1; o >>= 1) ps += __shfl_xor(ps, o);
    if (tid == 0) {
      float pt = AUX[tgt[b]];
      float tp = fmaxf(pt / ps, 1e-12f);
      ws[b] = -logf(tp) * (1.0f / (float)NQQ);
    }
  }
#undef STORE_TILE
#undef PROD
}

// Deterministic 1024 -> 1 mean.
__global__ __launch_bounds__(256) void reduce_k(const float* __restrict__ ws,
                                                float* __restrict__ out)
{
  __shared__ float s[256];
  const int tid = threadIdx.x;
  float v = ws[tid] + ws[tid + 256] + ws[tid + 512] + ws[tid + 768];
  s[tid] = v;
  __syncthreads();
  for (int o = 128; o > 0; o >>= 1) {
    if (tid < o) s[tid] += s[tid + o];
    __syncthreads();
  }
  if (tid == 0) out[0] = s[0] * (1.0f / (float)NB);
}

extern "C" void kernel_launch(void* const* d_in, const int* in_sizes, int n_in,
                              void* d_out, int out_size, void* d_ws, size_t ws_size,
                              hipStream_t stream) {
  const float* flat  = (const float*)d_in[0];
  const float* tv    = (const float*)d_in[1];
  const float* st    = (const float*)d_in[2];
  const int*   tgt   = (const int*)d_in[3];
  const int*   basis = (const int*)d_in[4];
  float* out = (float*)d_out;
  float* ws  = (float*)d_ws;

  hipLaunchKernelGGL(loss_k, dim3(NB), dim3(1024), 0, stream,
                     flat, tv, st, tgt, basis, ws);
  hipLaunchKernelGGL(reduce_k, dim3(1), dim3(256), 0, stream, ws, out);
}